// Round 9
// baseline (251.575 us; speedup 1.0000x reference)
//
#include <hip/hip_runtime.h>
#include <hip/hip_bf16.h>
#include <cmath>

#define NFEAT 1024
#define NHID  512
#define NLAYERS 8
#define NDIA 48
#define DIAL 64
#define NROW (NDIA*DIAL)   // 3072
#define NROW3 (3*NROW)     // 9216

typedef short bf16x8 __attribute__((ext_vector_type(8)));
typedef float f32x4  __attribute__((ext_vector_type(4)));
typedef unsigned short u16x8 __attribute__((ext_vector_type(8)));
typedef unsigned short u16x4 __attribute__((ext_vector_type(4)));
typedef unsigned short ushort_t;

__device__ __forceinline__ unsigned short f2bf(float x) {
  __hip_bfloat16 h = __float2bfloat16(x);
  return __builtin_bit_cast(unsigned short, h);
}
__device__ __forceinline__ float bf2f(unsigned short u) {
  __hip_bfloat16 h = __builtin_bit_cast(__hip_bfloat16, u);
  return __bfloat162float(h);
}

__device__ __forceinline__ void gload16(const void* g, void* l) {
  __builtin_amdgcn_global_load_lds(
      (const __attribute__((address_space(1))) void*)g,
      (__attribute__((address_space(3))) void*)l, 16, 0, 0);
}

// ---------- fused: row-norm + bf16 convert (raw and normalized) ----------
__global__ __launch_bounds__(256) void k_prep(const float* __restrict__ a, const float* __restrict__ v,
                      const float* __restrict__ l, ushort_t* __restrict__ Abuf,
                      ushort_t* __restrict__ Xn) {
  int gid = blockIdx.x * 256 + threadIdx.x;
  int row = gid >> 6, lane = gid & 63;
  int m = row / NROW, r = row % NROW;
  const float* src = (m == 0 ? a : (m == 1 ? v : l)) + (size_t)r * NFEAT;
  float4 x[4];
  float s = 0.f;
#pragma unroll
  for (int q = 0; q < 4; ++q) {
    x[q] = *reinterpret_cast<const float4*>(src + lane * 4 + q * 256);
    s += x[q].x*x[q].x + x[q].y*x[q].y + x[q].z*x[q].z + x[q].w*x[q].w;
  }
#pragma unroll
  for (int off = 32; off; off >>= 1) s += __shfl_xor(s, off);
  float inv = rsqrtf(s);
  ushort_t* da = Abuf + (size_t)row * NFEAT;
  ushort_t* dn = Xn + (size_t)row * NFEAT;
#pragma unroll
  for (int q = 0; q < 4; ++q) {
    u16x4 oa, on;
    oa[0] = f2bf(x[q].x); oa[1] = f2bf(x[q].y); oa[2] = f2bf(x[q].z); oa[3] = f2bf(x[q].w);
    on[0] = f2bf(x[q].x * inv); on[1] = f2bf(x[q].y * inv);
    on[2] = f2bf(x[q].z * inv); on[3] = f2bf(x[q].w * inv);
    *reinterpret_cast<u16x4*>(da + lane * 4 + q * 256) = oa;
    *reinterpret_cast<u16x4*>(dn + lane * 4 + q * 256) = on;
  }
}

// ---------- MFMA Gram -> acos -> fused degree+normalize -> bf16 S + dinv ----------
__global__ __launch_bounds__(256) void k_simm(const ushort_t* __restrict__ Xn,
                      ushort_t* __restrict__ Sbf, float* __restrict__ dinv) {
  __shared__ short Xs[2][4096];
  __shared__ float simS[64][73];
  int blk = blockIdx.x;
  const ushort_t* Xb = Xn + (size_t)blk * 64 * NFEAT;
  int t = threadIdx.x, w = t >> 6, lane = t & 63;
  f32x4 acc[4] = {};

#define STAGE_SIM(b, k0) do { \
    _Pragma("unroll") \
    for (int q = 0; q < 2; ++q) { \
      int f_ = t * 8 + q * 2048; \
      int row_ = f_ >> 6; \
      int col_ = (f_ & 63) ^ ((row_ & 7) << 3); \
      gload16(Xb + (size_t)row_ * NFEAT + (k0) + col_, (void*)(Xs[b] + q * 2048 + w * 512)); \
    } } while (0)

  STAGE_SIM(0, 0);
  __syncthreads();
  for (int it = 0; it < 16; ++it) {
    int cur = it & 1;
    if (it < 15) STAGE_SIM(cur ^ 1, (it + 1) * 64);
    const char* base = (const char*)Xs[cur];
#pragma unroll
    for (int ks = 0; ks < 2; ++ks) {
      int koff = ks * 32 + (lane >> 4) * 8;
      int arow = w * 16 + (lane & 15);
      bf16x8 af = *(const bf16x8*)(base + (((arow << 7) + (koff << 1)) ^ ((arow & 7) << 4)));
#pragma unroll
      for (int j = 0; j < 4; ++j) {
        int brow = j * 16 + (lane & 15);
        bf16x8 bf = *(const bf16x8*)(base + (((brow << 7) + (koff << 1)) ^ ((brow & 7) << 4)));
        acc[j] = __builtin_amdgcn_mfma_f32_16x16x32_bf16(af, bf, acc[j], 0, 0, 0);
      }
    }
    __syncthreads();
  }
#undef STAGE_SIM

#pragma unroll
  for (int j = 0; j < 4; ++j)
#pragma unroll
    for (int e = 0; e < 4; ++e) {
      int r = w * 16 + (lane >> 4) * 4 + e;
      int c = j * 16 + (lane & 15);
      float cc = acc[j][e] * 0.99999f;
      cc = fminf(fmaxf(cc, -0.99999f), 0.99999f);
      simS[r][c] = acosf(cc);
    }
  __syncthreads();
  if (t < 64) {
    float s = 0.f;
#pragma unroll 8
    for (int c = 0; c < 64; ++c) s += simS[t][c];
    float di = rsqrtf(s + 1.99998f);
    simS[t][64] = di;
    dinv[blk * 64 + t] = di;
  }
  __syncthreads();
  ushort_t* Sb = Sbf + (size_t)blk * 4096;
#pragma unroll
  for (int q = 0; q < 2; ++q) {
    int idx = t * 8 + q * 2048;
    int i = idx >> 6, j0 = idx & 63;
    float di = simS[i][64];
    u16x8 o;
#pragma unroll
    for (int e = 0; e < 8; ++e)
      o[e] = f2bf(simS[i][j0 + e] * di * simS[j0 + e][64]);
    *reinterpret_cast<u16x8*>(Sb + idx) = o;
  }
}

// ---------- transpose+convert weights: src f32 [K][512] -> dst bf16 [512][K] ----------
__global__ void k_cvt_w(const float* __restrict__ s0, const float* __restrict__ s1,
                        const float* __restrict__ s2, ushort_t* __restrict__ dst,
                        int K, int mode) {
  __shared__ float tile[32][33];
  int z = blockIdx.z;
  const float* src = (mode == 1) ? (s0 + (size_t)z * K * NHID)
                                 : (z == 0 ? s0 : (z == 1 ? s1 : s2));
  ushort_t* d = dst + (size_t)z * NHID * K;
  int n0 = blockIdx.x * 32, k0 = blockIdx.y * 32;
  int tx = threadIdx.x & 31, ty = threadIdx.x >> 5;
#pragma unroll
  for (int q = 0; q < 4; ++q)
    tile[ty + q * 8][tx] = src[(size_t)(k0 + ty + q * 8) * NHID + n0 + tx];
  __syncthreads();
#pragma unroll
  for (int q = 0; q < 4; ++q)
    d[(size_t)(n0 + ty + q * 8) * K + k0 + tx] = f2bf(tile[tx][ty + q * 8]);
}

// ---------- bf16 MFMA GEMM, tile 128x128, BK=64, 2-phase double-buffered ----------
// 4 waves, each computes a 64x64 quadrant. Grid (M/128, 512/128).
// EPI 0: relu(acc + bias[col]) -> C and C2 (band-selected B/bias, K=1024)
// EPI 1: relu(theta*acc + (1-theta)*sup[row][col]) -> C (K=512)
template<int EPI>
__global__ __launch_bounds__(256) void k_gemm_mfma(
    const ushort_t* __restrict__ A, const ushort_t* __restrict__ B,
    const float* __restrict__ ba, const float* __restrict__ bv, const float* __restrict__ bl,
    const ushort_t* __restrict__ sup, ushort_t* __restrict__ C, ushort_t* __restrict__ C2,
    int K, float theta) {
  __shared__ short As[2][128 * 64];
  __shared__ short Bs[2][128 * 64];
  int t = threadIdx.x;
  int w = t >> 6, lane = t & 63;
  int bm = blockIdx.x * 128, bn = blockIdx.y * 128;
  const float* bias = ba;
  if (EPI == 0) {
    int band = bm / NROW;
    B += (size_t)band * NHID * K;
    bias = (band == 0 ? ba : (band == 1 ? bv : bl));
  }
  const ushort_t* Ab = A + (size_t)bm * K;
  const ushort_t* Bb = B + (size_t)bn * K;
  int wr = (w >> 1) * 64, wc = (w & 1) * 64;
  f32x4 acc[4][4] = {};

#define STAGE_G(b, k0) do { \
    _Pragma("unroll") \
    for (int q = 0; q < 4; ++q) { \
      int f_ = t * 8 + q * 2048; int row_ = f_ >> 6; \
      int col_ = (f_ & 63) ^ ((row_ & 7) << 3); \
      gload16(Ab + (size_t)row_ * K + (k0) + col_, (void*)(As[b] + q * 2048 + w * 512)); } \
    _Pragma("unroll") \
    for (int q = 0; q < 4; ++q) { \
      int f_ = t * 8 + q * 2048; int row_ = f_ >> 6; \
      int col_ = (f_ & 63) ^ ((row_ & 7) << 3); \
      gload16(Bb + (size_t)row_ * K + (k0) + col_, (void*)(Bs[b] + q * 2048 + w * 512)); } \
  } while (0)

  STAGE_G(0, 0);
  __syncthreads();
  int T = K >> 6;
  for (int s = 0; s < T; ++s) {
    int cur = s & 1;
    if (s + 1 < T) STAGE_G(cur ^ 1, (s + 1) * 64);   // prefetch overlaps compute
    const char* ab = (const char*)As[cur];
    const char* bb = (const char*)Bs[cur];
#pragma unroll
    for (int ks = 0; ks < 2; ++ks) {
      int koff = ks * 32 + (lane >> 4) * 8;
      bf16x8 af[4], bfr[4];
#pragma unroll
      for (int i = 0; i < 4; ++i) {
        int arow = wr + i * 16 + (lane & 15);
        af[i] = *reinterpret_cast<const bf16x8*>(ab +
                  (((arow << 7) + (koff << 1)) ^ ((arow & 7) << 4)));
      }
#pragma unroll
      for (int j = 0; j < 4; ++j) {
        int brow = wc + j * 16 + (lane & 15);
        bfr[j] = *reinterpret_cast<const bf16x8*>(bb +
                  (((brow << 7) + (koff << 1)) ^ ((brow & 7) << 4)));
      }
#pragma unroll
      for (int i = 0; i < 4; ++i)
#pragma unroll
        for (int j = 0; j < 4; ++j)
          acc[i][j] = __builtin_amdgcn_mfma_f32_16x16x32_bf16(af[i], bfr[j], acc[i][j], 0, 0, 0);
    }
    __syncthreads();   // drains vmcnt: next tile staged and ready
  }
#undef STAGE_G

#pragma unroll
  for (int i = 0; i < 4; ++i) {
#pragma unroll
    for (int jf = 0; jf < 4; ++jf) {
      int r0 = bm + wr + i * 16 + (lane >> 4) * 4;
      int c  = bn + wc + jf * 16 + (lane & 15);
#pragma unroll
      for (int j = 0; j < 4; ++j) {
        int r = r0 + j;
        float val = acc[i][jf][j];
        if (EPI == 0) {
          val = fmaxf(val + bias[c], 0.f);
          unsigned short o = f2bf(val);
          C[(size_t)r * NHID + c] = o;
          C2[(size_t)r * NHID + c] = o;
        } else {
          float s = bf2f(sup[(size_t)r * NHID + c]);
          val = fmaxf(theta * val + (1.f - theta) * s, 0.f);
          C[(size_t)r * NHID + c] = f2bf(val);
        }
      }
    }
  }
}

// ---------- modality-grouped MFMA block-sparse adj@h + cross + h0 residual ----------
// block = (dialogue d, 64-col chunk): all 3 modality 64x64 S-blocks (round-4 form)
__global__ __launch_bounds__(256) void k_adj(const ushort_t* __restrict__ Sbf,
                      const ushort_t* __restrict__ h, const ushort_t* __restrict__ h0,
                      const float* __restrict__ dinv, ushort_t* __restrict__ sup) {
  __shared__ short Ss[3 * 4096];      // swizzled S blocks
  __shared__ short Ht[3][64][72];     // Ht[m][n][j'] = h[m,row j][col n], j' = j ^ key(n)
  __shared__ float supS[64][69];      // stride 69: gcd(5,32)=1 -> conflict-free
  int d = blockIdx.x, c0 = blockIdx.y * 64;
  int t = threadIdx.x, w = t >> 6, lane = t & 63;
#pragma unroll
  for (int q = 0; q < 6; ++q) {
    int f = t * 8 + q * 2048;
    int mod = f >> 12, rem = f & 4095;
    int row = rem >> 6;
    int col = (rem & 63) ^ ((row & 7) << 3);
    gload16(Sbf + ((size_t)(mod * NDIA + d)) * 4096 + row * 64 + col,
            (void*)(Ss + q * 2048 + w * 512));
  }
#pragma unroll
  for (int q = 0; q < 6; ++q) {
    int idx = t + q * 256;            // 0..1535
    int mod = idx >> 9, rem = idx & 511;
    int j = rem >> 3, n0 = (rem & 7) * 8;
    int key = rem & 7;                // = n0>>3
    u16x8 hv = *reinterpret_cast<const u16x8*>(
        h + ((size_t)(mod * NROW + d * 64 + j)) * NHID + c0 + n0);
    int js = j ^ (key << 3);
#pragma unroll
    for (int e = 0; e < 8; ++e) Ht[mod][n0 + e][js] = hv[e];
  }
  __syncthreads();
  f32x4 acc[3][4] = {};
#pragma unroll
  for (int m = 0; m < 3; ++m)
#pragma unroll
    for (int ks = 0; ks < 2; ++ks) {
      int koff = ks * 32 + (lane >> 4) * 8;
      int arow = w * 16 + (lane & 15);
      bf16x8 af = *(const bf16x8*)((const char*)Ss + m * 8192 +
                    (((arow << 7) + (koff << 1)) ^ ((arow & 7) << 4)));
#pragma unroll
      for (int j = 0; j < 4; ++j) {
        int n = j * 16 + (lane & 15);
        int koff_s = koff ^ (((n >> 3) & 7) << 3);
        bf16x8 bf = *(const bf16x8*)(&Ht[m][n][koff_s]);
        acc[m][j] = __builtin_amdgcn_mfma_f32_16x16x32_bf16(af, bf, acc[m][j], 0, 0, 0);
      }
    }
  // epilogue, one modality at a time through supS
  int r = t >> 2, cc0 = (t & 3) * 16;
  int u = d * 64 + r;
  float d0 = dinv[u], d1 = dinv[NROW + u], d2 = dinv[2 * NROW + u];
  float dv[3] = {d0, d1, d2};
  for (int m = 0; m < 3; ++m) {
#pragma unroll
    for (int j = 0; j < 4; ++j)
#pragma unroll
      for (int e = 0; e < 4; ++e)
        supS[w * 16 + (lane >> 4) * 4 + e][j * 16 + (lane & 15)] = acc[m][j][e];
    __syncthreads();
    int mm1 = (m + 1) % 3, mm2 = (m + 2) % 3;
    int g = m * NROW + u;
    float c1 = 0.99999f * dv[m] * dv[mm1];
    float c2 = 0.99999f * dv[m] * dv[mm2];
    const ushort_t* p1 = h + ((size_t)(mm1 * NROW + u)) * NHID + c0 + cc0;
    const ushort_t* p2 = h + ((size_t)(mm2 * NROW + u)) * NHID + c0 + cc0;
    const ushort_t* pz = h0 + (size_t)g * NHID + c0 + cc0;
    ushort_t* po = sup + (size_t)g * NHID + c0 + cc0;
#pragma unroll
    for (int half = 0; half < 2; ++half) {
      u16x8 h1 = *reinterpret_cast<const u16x8*>(p1 + half * 8);
      u16x8 h2 = *reinterpret_cast<const u16x8*>(p2 + half * 8);
      u16x8 hz = *reinterpret_cast<const u16x8*>(pz + half * 8);
      u16x8 o;
#pragma unroll
      for (int e = 0; e < 8; ++e) {
        float val = 0.9f * (supS[r][cc0 + half * 8 + e] + c1 * bf2f(h1[e]) + c2 * bf2f(h2[e]))
                  + 0.1f * bf2f(hz[e]);
        o[e] = f2bf(val);
      }
      *reinterpret_cast<u16x8*>(po + half * 8) = o;
    }
    __syncthreads();
  }
}

// ---------- assemble output: [ l(f32) | h(bf16->f32) ] ----------
__global__ void k_out(const float* __restrict__ l, const ushort_t* __restrict__ h,
                      float* __restrict__ out) {
  int idx = blockIdx.x * blockDim.x + threadIdx.x;
  int i = idx / 640;
  int c4 = (idx % 640) * 4;
  float4 val;
  if (c4 < 1024) {
    val = *reinterpret_cast<const float4*>(l + (size_t)i * NFEAT + c4);
  } else {
    int cc = c4 - 1024;
    int m = cc >> 9, c = cc & 511;
    u16x4 hv = *reinterpret_cast<const u16x4*>(h + ((size_t)m * NROW + i) * NHID + c);
    val.x = bf2f(hv[0]); val.y = bf2f(hv[1]); val.z = bf2f(hv[2]); val.w = bf2f(hv[3]);
  }
  *reinterpret_cast<float4*>(out + (size_t)i * 2560 + c4) = val;
}

extern "C" void kernel_launch(void* const* d_in, const int* in_sizes, int n_in,
                              void* d_out, int out_size, void* d_ws, size_t ws_size,
                              hipStream_t stream) {
  const float* a  = (const float*)d_in[0];
  const float* v  = (const float*)d_in[1];
  const float* l  = (const float*)d_in[2];
  const float* W0 = (const float*)d_in[3];
  const float* b0 = (const float*)d_in[4];
  const float* W1 = (const float*)d_in[5];
  const float* b1 = (const float*)d_in[6];
  const float* W2 = (const float*)d_in[7];
  const float* b2 = (const float*)d_in[8];
  const float* Wc = (const float*)d_in[9];
  float* out = (float*)d_out;

  const size_t SZ = (size_t)NROW3 * NHID;             // 4,718,592 elements
  const size_t XSZ = (size_t)3 * NROW * NFEAT;        // 9,437,184 elements
  char* ws = (char*)d_ws;
  ushort_t* Abuf = (ushort_t*)ws;  ws += XSZ * 2;     // raw bf16 inputs (live through FC)
  ushort_t* Xn   = (ushort_t*)ws;  ws += XSZ * 2;     // normalized; dead after k_simm
  ushort_t* h0   = (ushort_t*)ws;  ws += SZ * 2;
  ushort_t* Wtfc = (ushort_t*)ws;  ws += (size_t)3 * NHID * NFEAT * 2;
  ushort_t* Wct  = (ushort_t*)ws;  ws += (size_t)NLAYERS * NHID * NHID * 2;
  ushort_t* Sbf  = (ushort_t*)ws;  ws += (size_t)144 * 4096 * 2;
  float* dinv    = (float*)ws;
  ushort_t* h   = Xn;            // alias: Xn dead once k_simm completes
  ushort_t* sup = Xn + SZ;       // both fit in Xn's footprint (2*SZ == XSZ)

  k_prep<<<NROW3 / 4, 256, 0, stream>>>(a, v, l, Abuf, Xn);
  k_cvt_w<<<dim3(NHID / 32, NFEAT / 32, 3), 256, 0, stream>>>(W0, W2, W1, Wtfc, NFEAT, 0);
  k_cvt_w<<<dim3(NHID / 32, NHID / 32, NLAYERS), 256, 0, stream>>>(Wc, nullptr, nullptr, Wct, NHID, 1);
  k_simm<<<3 * NDIA, 256, 0, stream>>>(Xn, Sbf, dinv);

  // fused FC -> writes BOTH h0 and h (no memcpy)
  k_gemm_mfma<0><<<dim3(NROW3 / 128, NHID / 128), 256, 0, stream>>>(
      Abuf, Wtfc, b0, b2, b1, nullptr, h0, h, NFEAT, 0.f);

  for (int i = 0; i < NLAYERS; ++i) {
    float theta = (float)std::log(0.5 / (i + 1) + 1.0);
    k_adj<<<dim3(NDIA, NHID / 64), 256, 0, stream>>>(Sbf, h, h0, dinv, sup);
    k_gemm_mfma<1><<<dim3(NROW3 / 128, NHID / 128), 256, 0, stream>>>(
        sup, Wct + (size_t)i * NHID * NHID, nullptr, nullptr, nullptr, sup, h, nullptr, NHID, theta);
  }

  k_out<<<(NROW * 2560 / 4) / 256, 256, 0, stream>>>(l, h, out);
}

// Round 10
// 229.528 us; speedup vs baseline: 1.0961x; 1.0961x over previous
//
#include <hip/hip_runtime.h>
#include <hip/hip_bf16.h>
#include <cmath>

#define NFEAT 1024
#define NHID  512
#define NLAYERS 8
#define NDIA 48
#define DIAL 64
#define NROW (NDIA*DIAL)   // 3072
#define NROW3 (3*NROW)     // 9216

typedef short bf16x8 __attribute__((ext_vector_type(8)));
typedef float f32x4  __attribute__((ext_vector_type(4)));
typedef unsigned short u16x8 __attribute__((ext_vector_type(8)));
typedef unsigned short u16x4 __attribute__((ext_vector_type(4)));
typedef unsigned short ushort_t;

__device__ __forceinline__ unsigned short f2bf(float x) {
  __hip_bfloat16 h = __float2bfloat16(x);
  return __builtin_bit_cast(unsigned short, h);
}
__device__ __forceinline__ float bf2f(unsigned short u) {
  __hip_bfloat16 h = __builtin_bit_cast(__hip_bfloat16, u);
  return __bfloat162float(h);
}

__device__ __forceinline__ void gload16(const void* g, void* l) {
  __builtin_amdgcn_global_load_lds(
      (const __attribute__((address_space(1))) void*)g,
      (__attribute__((address_space(3))) void*)l, 16, 0, 0);
}

// ---------- fused: row-norm scalar + raw bf16 convert ----------
__global__ __launch_bounds__(256) void k_prep(const float* __restrict__ a, const float* __restrict__ v,
                      const float* __restrict__ l, ushort_t* __restrict__ Abuf,
                      float* __restrict__ invn) {
  int gid = blockIdx.x * 256 + threadIdx.x;
  int row = gid >> 6, lane = gid & 63;
  int m = row / NROW, r = row % NROW;
  const float* src = (m == 0 ? a : (m == 1 ? v : l)) + (size_t)r * NFEAT;
  float4 x[4];
  float s = 0.f;
#pragma unroll
  for (int q = 0; q < 4; ++q) {
    x[q] = *reinterpret_cast<const float4*>(src + lane * 4 + q * 256);
    s += x[q].x*x[q].x + x[q].y*x[q].y + x[q].z*x[q].z + x[q].w*x[q].w;
  }
#pragma unroll
  for (int off = 32; off; off >>= 1) s += __shfl_xor(s, off);
  if (lane == 0) invn[row] = rsqrtf(s);
  ushort_t* da = Abuf + (size_t)row * NFEAT;
#pragma unroll
  for (int q = 0; q < 4; ++q) {
    u16x4 oa;
    oa[0] = f2bf(x[q].x); oa[1] = f2bf(x[q].y); oa[2] = f2bf(x[q].z); oa[3] = f2bf(x[q].w);
    *reinterpret_cast<u16x4*>(da + lane * 4 + q * 256) = oa;
  }
}

// ---------- MFMA Gram (raw bf16) -> scale by invn -> acos -> degree+normalize ----------
__global__ __launch_bounds__(256) void k_simm(const ushort_t* __restrict__ Ab,
                      const float* __restrict__ invn,
                      ushort_t* __restrict__ Sbf, float* __restrict__ dinv) {
  __shared__ short Xs[2][4096];
  __shared__ float simS[64][73];
  __shared__ float invS[64];
  int blk = blockIdx.x;
  const ushort_t* Xb = Ab + (size_t)blk * 64 * NFEAT;
  int t = threadIdx.x, w = t >> 6, lane = t & 63;
  if (t < 64) invS[t] = invn[blk * 64 + t];
  f32x4 acc[4] = {};

#define STAGE_SIM(b, k0) do { \
    _Pragma("unroll") \
    for (int q = 0; q < 2; ++q) { \
      int f_ = t * 8 + q * 2048; \
      int row_ = f_ >> 6; \
      int col_ = (f_ & 63) ^ ((row_ & 7) << 3); \
      gload16(Xb + (size_t)row_ * NFEAT + (k0) + col_, (void*)(Xs[b] + q * 2048 + w * 512)); \
    } } while (0)

  STAGE_SIM(0, 0);
  __syncthreads();
  for (int it = 0; it < 16; ++it) {
    int cur = it & 1;
    if (it < 15) STAGE_SIM(cur ^ 1, (it + 1) * 64);
    const char* base = (const char*)Xs[cur];
#pragma unroll
    for (int ks = 0; ks < 2; ++ks) {
      int koff = ks * 32 + (lane >> 4) * 8;
      int arow = w * 16 + (lane & 15);
      bf16x8 af = *(const bf16x8*)(base + (((arow << 7) + (koff << 1)) ^ ((arow & 7) << 4)));
#pragma unroll
      for (int j = 0; j < 4; ++j) {
        int brow = j * 16 + (lane & 15);
        bf16x8 bf = *(const bf16x8*)(base + (((brow << 7) + (koff << 1)) ^ ((brow & 7) << 4)));
        acc[j] = __builtin_amdgcn_mfma_f32_16x16x32_bf16(af, bf, acc[j], 0, 0, 0);
      }
    }
    __syncthreads();
  }
#undef STAGE_SIM

#pragma unroll
  for (int j = 0; j < 4; ++j)
#pragma unroll
    for (int e = 0; e < 4; ++e) {
      int r = w * 16 + (lane >> 4) * 4 + e;
      int c = j * 16 + (lane & 15);
      float cc = acc[j][e] * invS[r] * invS[c] * 0.99999f;
      cc = fminf(fmaxf(cc, -0.99999f), 0.99999f);
      simS[r][c] = acosf(cc);
    }
  __syncthreads();
  if (t < 64) {
    float s = 0.f;
#pragma unroll 8
    for (int c = 0; c < 64; ++c) s += simS[t][c];
    float di = rsqrtf(s + 1.99998f);
    simS[t][64] = di;
    dinv[blk * 64 + t] = di;
  }
  __syncthreads();
  ushort_t* Sb = Sbf + (size_t)blk * 4096;
#pragma unroll
  for (int q = 0; q < 2; ++q) {
    int idx = t * 8 + q * 2048;
    int i = idx >> 6, j0 = idx & 63;
    float di = simS[i][64];
    u16x8 o;
#pragma unroll
    for (int e = 0; e < 8; ++e)
      o[e] = f2bf(simS[i][j0 + e] * di * simS[j0 + e][64]);
    *reinterpret_cast<u16x8*>(Sb + idx) = o;
  }
}

// ---------- transpose+convert weights: src f32 [K][512] -> dst bf16 [512][K] ----------
__global__ void k_cvt_w(const float* __restrict__ s0, const float* __restrict__ s1,
                        const float* __restrict__ s2, ushort_t* __restrict__ dst,
                        int K, int mode) {
  __shared__ float tile[32][33];
  int z = blockIdx.z;
  const float* src = (mode == 1) ? (s0 + (size_t)z * K * NHID)
                                 : (z == 0 ? s0 : (z == 1 ? s1 : s2));
  ushort_t* d = dst + (size_t)z * NHID * K;
  int n0 = blockIdx.x * 32, k0 = blockIdx.y * 32;
  int tx = threadIdx.x & 31, ty = threadIdx.x >> 5;
#pragma unroll
  for (int q = 0; q < 4; ++q)
    tile[ty + q * 8][tx] = src[(size_t)(k0 + ty + q * 8) * NHID + n0 + tx];
  __syncthreads();
#pragma unroll
  for (int q = 0; q < 4; ++q)
    d[(size_t)(n0 + ty + q * 8) * K + k0 + tx] = f2bf(tile[tx][ty + q * 8]);
}

// ---------- bf16 MFMA GEMM, tile 128x64, BK=64, 2-phase double-buffered ----------
// EPI 0: relu(acc + bias[col]) -> C and C2 ; EPI 1: relu(theta*acc + (1-theta)*sup)
template<int EPI>
__global__ __launch_bounds__(256) void k_gemm_mfma(
    const ushort_t* __restrict__ A, const ushort_t* __restrict__ B,
    const float* __restrict__ ba, const float* __restrict__ bv, const float* __restrict__ bl,
    const ushort_t* __restrict__ sup, ushort_t* __restrict__ C, ushort_t* __restrict__ C2,
    int K, float theta) {
  __shared__ short As[2][128 * 64];
  __shared__ short Bs[2][64 * 64];
  int t = threadIdx.x;
  int w = t >> 6, lane = t & 63;
  int bm = blockIdx.x * 128, bn = blockIdx.y * 64;
  const float* bias = ba;
  if (EPI == 0) {
    int band = bm / NROW;
    B += (size_t)band * NHID * K;
    bias = (band == 0 ? ba : (band == 1 ? bv : bl));
  }
  const ushort_t* Ab = A + (size_t)bm * K;
  const ushort_t* Bb = B + (size_t)bn * K;
  int wr = (w >> 1) * 64, wc = (w & 1) * 32;
  f32x4 acc[4][2] = {};

#define STAGE_G(b, k0) do { \
    _Pragma("unroll") \
    for (int q = 0; q < 4; ++q) { \
      int f_ = t * 8 + q * 2048; int row_ = f_ >> 6; \
      int col_ = (f_ & 63) ^ ((row_ & 7) << 3); \
      gload16(Ab + (size_t)row_ * K + (k0) + col_, (void*)(As[b] + q * 2048 + w * 512)); } \
    _Pragma("unroll") \
    for (int q = 0; q < 2; ++q) { \
      int f_ = t * 8 + q * 2048; int row_ = f_ >> 6; \
      int col_ = (f_ & 63) ^ ((row_ & 7) << 3); \
      gload16(Bb + (size_t)row_ * K + (k0) + col_, (void*)(Bs[b] + q * 2048 + w * 512)); } \
  } while (0)

  STAGE_G(0, 0);
  __syncthreads();
  int T = K >> 6;
  for (int s = 0; s < T; ++s) {
    int cur = s & 1;
    if (s + 1 < T) STAGE_G(cur ^ 1, (s + 1) * 64);   // prefetch overlaps compute
    const char* ab = (const char*)As[cur];
    const char* bb = (const char*)Bs[cur];
#pragma unroll
    for (int ks = 0; ks < 2; ++ks) {
      bf16x8 af[4], bfr[2];
#pragma unroll
      for (int i = 0; i < 4; ++i) {
        int arow = wr + i * 16 + (lane & 15);
        int abo = (arow << 7) + ((ks * 32 + (lane >> 4) * 8) << 1);
        af[i] = *reinterpret_cast<const bf16x8*>(ab + (abo ^ ((arow & 7) << 4)));
      }
#pragma unroll
      for (int j = 0; j < 2; ++j) {
        int brow = wc + j * 16 + (lane & 15);
        int bbo = (brow << 7) + ((ks * 32 + (lane >> 4) * 8) << 1);
        bfr[j] = *reinterpret_cast<const bf16x8*>(bb + (bbo ^ ((brow & 7) << 4)));
      }
#pragma unroll
      for (int i = 0; i < 4; ++i)
#pragma unroll
        for (int j = 0; j < 2; ++j)
          acc[i][j] = __builtin_amdgcn_mfma_f32_16x16x32_bf16(af[i], bfr[j], acc[i][j], 0, 0, 0);
    }
    __syncthreads();   // drains vmcnt: next tile staged and ready
  }
#undef STAGE_G

#pragma unroll
  for (int i = 0; i < 4; ++i) {
#pragma unroll
    for (int jf = 0; jf < 2; ++jf) {
      int r0 = bm + wr + i * 16 + (lane >> 4) * 4;
      int c  = bn + wc + jf * 16 + (lane & 15);
#pragma unroll
      for (int j = 0; j < 4; ++j) {
        int r = r0 + j;
        float val = acc[i][jf][j];
        if (EPI == 0) {
          val = fmaxf(val + bias[c], 0.f);
          unsigned short o = f2bf(val);
          C[(size_t)r * NHID + c] = o;
          C2[(size_t)r * NHID + c] = o;
        } else {
          float s = bf2f(sup[(size_t)r * NHID + c]);
          val = fmaxf(theta * val + (1.f - theta) * s, 0.f);
          C[(size_t)r * NHID + c] = f2bf(val);
        }
      }
    }
  }
}

// ---------- modality-grouped MFMA block-sparse adj@h + cross + h0 residual ----------
// LDS overlay: staging {Ss 24576B + Ht 27648B} == epilogue supF[192][68] f32 (52224B)
__global__ __launch_bounds__(256) void k_adj(const ushort_t* __restrict__ Sbf,
                      const ushort_t* __restrict__ h, const ushort_t* __restrict__ h0,
                      const float* __restrict__ dinv, ushort_t* __restrict__ sup) {
  __shared__ char ldsb[52224];
  short* Ss = (short*)ldsb;                           // [3*4096]
  short (*Ht)[72] = (short (*)[72])(ldsb + 24576);    // [192][72]
  float (*supF)[68] = (float (*)[68])ldsb;            // overlay [192][68] f32
  int d = blockIdx.x, c0 = blockIdx.y * 64;
  int t = threadIdx.x, w = t >> 6, lane = t & 63;
#pragma unroll
  for (int q = 0; q < 6; ++q) {
    int f = t * 8 + q * 2048;
    int mod = f >> 12, rem = f & 4095;
    int row = rem >> 6;
    int col = (rem & 63) ^ ((row & 7) << 3);
    gload16(Sbf + ((size_t)(mod * NDIA + d)) * 4096 + row * 64 + col,
            (void*)(Ss + q * 2048 + w * 512));
  }
#pragma unroll
  for (int q = 0; q < 6; ++q) {
    int idx = t + q * 256;            // 0..1535
    int mod = idx >> 9, rem = idx & 511;
    int j = rem >> 3, n0 = (rem & 7) * 8;
    int key = rem & 7;                // = n0>>3
    u16x8 hv = *reinterpret_cast<const u16x8*>(
        h + ((size_t)(mod * NROW + d * 64 + j)) * NHID + c0 + n0);
    int js = j ^ (key << 3);
#pragma unroll
    for (int e = 0; e < 8; ++e) Ht[mod * 64 + n0 + e][js] = hv[e];
  }
  __syncthreads();
  f32x4 acc[3][4] = {};
#pragma unroll
  for (int m = 0; m < 3; ++m)
#pragma unroll
    for (int ks = 0; ks < 2; ++ks) {
      int koff = ks * 32 + (lane >> 4) * 8;
      int arow = w * 16 + (lane & 15);
      bf16x8 af = *(const bf16x8*)((const char*)Ss + m * 8192 +
                    (((arow << 7) + (koff << 1)) ^ ((arow & 7) << 4)));
#pragma unroll
      for (int j = 0; j < 4; ++j) {
        int n = j * 16 + (lane & 15);
        int koff_s = koff ^ (((n >> 3) & 7) << 3);
        bf16x8 bf = *(const bf16x8*)(&Ht[m * 64 + n][koff_s]);
        acc[m][j] = __builtin_amdgcn_mfma_f32_16x16x32_bf16(af, bf, acc[m][j], 0, 0, 0);
      }
    }
  __syncthreads();            // all Ss/Ht reads done -> safe to overlay
#pragma unroll
  for (int m = 0; m < 3; ++m)
#pragma unroll
    for (int j = 0; j < 4; ++j)
#pragma unroll
      for (int e = 0; e < 4; ++e)
        supF[m * 64 + w * 16 + (lane >> 4) * 4 + e][j * 16 + (lane & 15)] = acc[m][j][e];
  __syncthreads();
  // coalesced epilogue: thread t -> row r = t>>2, 16 cols at (t&3)*16, all 3 modalities
  int r = t >> 2, cc0 = (t & 3) * 16;
  int u = d * 64 + r;
  float dv[3] = {dinv[u], dinv[NROW + u], dinv[2 * NROW + u]};
#pragma unroll
  for (int m = 0; m < 3; ++m) {
    int mm1 = (m + 1) % 3, mm2 = (m + 2) % 3;
    int g = m * NROW + u;
    float c1 = 0.99999f * dv[m] * dv[mm1];
    float c2 = 0.99999f * dv[m] * dv[mm2];
    const ushort_t* p1 = h + ((size_t)(mm1 * NROW + u)) * NHID + c0 + cc0;
    const ushort_t* p2 = h + ((size_t)(mm2 * NROW + u)) * NHID + c0 + cc0;
    const ushort_t* pz = h0 + (size_t)g * NHID + c0 + cc0;
    ushort_t* po = sup + (size_t)g * NHID + c0 + cc0;
#pragma unroll
    for (int half = 0; half < 2; ++half) {
      u16x8 h1 = *reinterpret_cast<const u16x8*>(p1 + half * 8);
      u16x8 h2 = *reinterpret_cast<const u16x8*>(p2 + half * 8);
      u16x8 hz = *reinterpret_cast<const u16x8*>(pz + half * 8);
      u16x8 o;
#pragma unroll
      for (int e = 0; e < 8; ++e) {
        float val = 0.9f * (supF[m * 64 + r][cc0 + half * 8 + e]
                    + c1 * bf2f(h1[e]) + c2 * bf2f(h2[e]))
                  + 0.1f * bf2f(hz[e]);
        o[e] = f2bf(val);
      }
      *reinterpret_cast<u16x8*>(po + half * 8) = o;
    }
  }
}

// ---------- assemble output: [ l(f32) | h(bf16->f32) ] ----------
__global__ void k_out(const float* __restrict__ l, const ushort_t* __restrict__ h,
                      float* __restrict__ out) {
  int idx = blockIdx.x * blockDim.x + threadIdx.x;
  int i = idx / 640;
  int c4 = (idx % 640) * 4;
  float4 val;
  if (c4 < 1024) {
    val = *reinterpret_cast<const float4*>(l + (size_t)i * NFEAT + c4);
  } else {
    int cc = c4 - 1024;
    int m = cc >> 9, c = cc & 511;
    u16x4 hv = *reinterpret_cast<const u16x4*>(h + ((size_t)m * NROW + i) * NHID + c);
    val.x = bf2f(hv[0]); val.y = bf2f(hv[1]); val.z = bf2f(hv[2]); val.w = bf2f(hv[3]);
  }
  *reinterpret_cast<float4*>(out + (size_t)i * 2560 + c4) = val;
}

extern "C" void kernel_launch(void* const* d_in, const int* in_sizes, int n_in,
                              void* d_out, int out_size, void* d_ws, size_t ws_size,
                              hipStream_t stream) {
  const float* a  = (const float*)d_in[0];
  const float* v  = (const float*)d_in[1];
  const float* l  = (const float*)d_in[2];
  const float* W0 = (const float*)d_in[3];
  const float* b0 = (const float*)d_in[4];
  const float* W1 = (const float*)d_in[5];
  const float* b1 = (const float*)d_in[6];
  const float* W2 = (const float*)d_in[7];
  const float* b2 = (const float*)d_in[8];
  const float* Wc = (const float*)d_in[9];
  float* out = (float*)d_out;

  const size_t SZ = (size_t)NROW3 * NHID;             // 4,718,592 elements
  const size_t XSZ = (size_t)3 * NROW * NFEAT;        // 9,437,184 elements
  char* ws = (char*)d_ws;
  ushort_t* Abuf = (ushort_t*)ws;  ws += XSZ * 2;     // raw bf16 inputs
  ushort_t* h0   = (ushort_t*)ws;  ws += SZ * 2;
  ushort_t* h    = (ushort_t*)ws;  ws += SZ * 2;
  ushort_t* sup  = (ushort_t*)ws;  ws += SZ * 2;
  ushort_t* Wtfc = (ushort_t*)ws;  ws += (size_t)3 * NHID * NFEAT * 2;
  ushort_t* Wct  = (ushort_t*)ws;  ws += (size_t)NLAYERS * NHID * NHID * 2;
  ushort_t* Sbf  = (ushort_t*)ws;  ws += (size_t)144 * 4096 * 2;
  float* dinv    = (float*)ws;     ws += (size_t)NROW3 * 4;
  float* invn    = (float*)ws;

  k_prep<<<NROW3 / 4, 256, 0, stream>>>(a, v, l, Abuf, invn);
  k_cvt_w<<<dim3(NHID / 32, NFEAT / 32, 3), 256, 0, stream>>>(W0, W2, W1, Wtfc, NFEAT, 0);
  k_cvt_w<<<dim3(NHID / 32, NHID / 32, NLAYERS), 256, 0, stream>>>(Wc, nullptr, nullptr, Wct, NHID, 1);
  k_simm<<<3 * NDIA, 256, 0, stream>>>(Abuf, invn, Sbf, dinv);

  // fused FC -> writes BOTH h0 and h (no memcpy)
  k_gemm_mfma<0><<<dim3(NROW3 / 128, NHID / 64), 256, 0, stream>>>(
      Abuf, Wtfc, b0, b2, b1, nullptr, h0, h, NFEAT, 0.f);

  for (int i = 0; i < NLAYERS; ++i) {
    float theta = (float)std::log(0.5 / (i + 1) + 1.0);
    k_adj<<<dim3(NDIA, NHID / 64), 256, 0, stream>>>(Sbf, h, h0, dinv, sup);
    k_gemm_mfma<1><<<dim3(NROW3 / 128, NHID / 64), 256, 0, stream>>>(
        sup, Wct + (size_t)i * NHID * NHID, nullptr, nullptr, nullptr, sup, h, nullptr, NHID, theta);
  }

  k_out<<<(NROW * 2560 / 4) / 256, 256, 0, stream>>>(l, h, out);
}